// Round 6
// baseline (259.325 us; speedup 1.0000x reference)
//
#include <hip/hip_runtime.h>
#include <cstdint>
#include <cstddef>

// LSTM cell: B=4096, IN=1024, H=1024
//   ifgo = h @ Wh^T + bh + x @ Wx^T    [4096 x 4096]
//   i,f,g,o = split(ifgo); c' = sig(f)*c + sig(i)*tanh(g); h' = o*tanh(c')
//
// Pipeline (2 dispatches):
//   1. convert: fp32->bf16 into interleaved K=2048 layout (A_cat=[h|x],
//      W_cat=[Wh|Wx]) with W rows permuted p=((j>>4)<<6)|(gate<<4)|(j&15)
//      so each wave's 64 output columns hold all 4 gates of 16 consecutive j.
//   2. gemm: bf16 MFMA, 128x128 tile, single-barrier double-buffered BK=32
//      K-loop (loads for iter k+1 in flight during MFMA of iter k), staged in
//      CHUNK-MAJOR LDS layout so fragment ds_reads are lane-linear
//      (conflict-free), fused fast-math gate epilogue.

#define NB   4096      // batch
#define KH   1024      // H (== IN)
#define KK   2048      // concatenated K
#define ARR_ELEMS 4194304  // 4096*1024

typedef __bf16 bf16x8 __attribute__((ext_vector_type(8)));
typedef float  f32x4  __attribute__((ext_vector_type(4)));

__device__ inline unsigned short f2bf(float f) {
    union { float f; unsigned int u; } v; v.f = f;
    unsigned int u = v.u;
    u += 0x7FFFu + ((u >> 16) & 1u);   // RNE
    return (unsigned short)(u >> 16);
}

// fast gates: v_exp_f32 + v_rcp_f32, no branches
__device__ inline float fsig(float v)  { return __builtin_amdgcn_rcpf(1.f + __expf(-v)); }
__device__ inline float ftanh(float v) { return 1.f - 2.f * __builtin_amdgcn_rcpf(1.f + __expf(2.f * v)); }

// ---------------------------------------------------------------- convert ---
// ws layout (bf16): A_cat (8M elems) | W_cat (8M elems)
__global__ void convert_kernel(const float* __restrict__ h, const float* __restrict__ x,
                               const float* __restrict__ Wh, const float* __restrict__ Wx,
                               unsigned short* __restrict__ A, unsigned short* __restrict__ W) {
    int idx = blockIdx.x * 256 + threadIdx.x;       // 0 .. 4M-1, 4 floats each
    int arr = idx >> 20;                            // which source array
    int off = (idx & 0xFFFFF) << 2;                 // element offset within array
    const float* src = (arr == 0) ? h : (arr == 1) ? x : (arr == 2) ? Wh : Wx;
    float4 v = *(const float4*)(src + off);
    unsigned int lo = (unsigned int)f2bf(v.x) | ((unsigned int)f2bf(v.y) << 16);
    unsigned int hi = (unsigned int)f2bf(v.z) | ((unsigned int)f2bf(v.w) << 16);
    uint2 packed; packed.x = lo; packed.y = hi;

    int row = off >> 10;                            // logical row
    int col = off & 1023;
    unsigned short* dst;
    size_t dstOff;
    if (arr < 2) {                                  // A_cat: [h | x] per row
        dst = A;
        dstOff = (size_t)row * KK + (arr == 1 ? 1024 : 0) + col;
    } else {                                        // W_cat: permuted rows, [Wh | Wx]
        int g = row >> 10, j = row & 1023;
        int p = ((j >> 4) << 6) | (g << 4) | (j & 15);
        dst = W;
        dstOff = (size_t)p * KK + (arr == 3 ? 1024 : 0) + col;
    }
    *(uint2*)(dst + dstOff) = packed;
}

// ------------------------------------------------------------------- gemm ---
// 256 threads (4 waves), each wave 64x64 via 4x4 MFMA 16x16x32 bf16.
// LDS is chunk-major per 16-row group g: elem addr = g*512 + lane*8 where
// lane = (kchunk<<4) | rowlow  -> fragment reads are uniform + lane*16B.
// Staging: wave w, slab s stages group g = s*4+w; lane loads global
// row 16g+(lane&15), K-bytes [(lane>>4)*16 .. +16).
__global__ void gemm_kernel(const unsigned short* __restrict__ A,
                            const unsigned short* __restrict__ W,
                            const float* __restrict__ bh,
                            const float* __restrict__ c,
                            float* __restrict__ out) {
    __shared__ __align__(16) unsigned short As[2 * 4096];   // 2 bufs x 128x32
    __shared__ __align__(16) unsigned short Bs[2 * 4096];

    const int tid  = threadIdx.x;
    const int wave = tid >> 6;
    const int lane = tid & 63;
    const int tileN = blockIdx.x;   // 0..31  (output cols / 128)
    const int tileM = blockIdx.y;   // 0..31  (output rows / 128)

    const unsigned short* gaB = A + (size_t)(tileM * 128 + wave * 16 + (lane & 15)) * KK + (lane >> 4) * 8;
    const unsigned short* gbB = W + (size_t)(tileN * 128 + wave * 16 + (lane & 15)) * KK + (lane >> 4) * 8;

    const int mg = (wave >> 1) * 4;      // A row-group base for this wave's fragments
    const int ng = (wave & 1) * 4;       // B row-group base

    f32x4 acc[4][4] = {};

#define STAGE(kt, buf) do {                                                        \
        const unsigned short* ga_ = gaB + (kt) * 32;                               \
        const unsigned short* gb_ = gbB + (kt) * 32;                               \
        _Pragma("unroll")                                                          \
        for (int s_ = 0; s_ < 2; ++s_) {                                           \
            __builtin_amdgcn_global_load_lds(                                      \
                (const __attribute__((address_space(1))) void*)(ga_ + (size_t)s_ * 64 * KK), \
                (__attribute__((address_space(3))) void*)(As + (buf) * 4096 + (s_ * 4 + wave) * 512), 16, 0, 0); \
            __builtin_amdgcn_global_load_lds(                                      \
                (const __attribute__((address_space(1))) void*)(gb_ + (size_t)s_ * 64 * KK), \
                (__attribute__((address_space(3))) void*)(Bs + (buf) * 4096 + (s_ * 4 + wave) * 512), 16, 0, 0); \
        }                                                                          \
    } while (0)

    STAGE(0, 0);

    for (int kt = 0; kt < 64; ++kt) {
        const int p = kt & 1;
        __syncthreads();                  // buf[p] loads landed; prior buf[p^1] reads done
        if (kt < 63) STAGE(kt + 1, p ^ 1);

        bf16x8 a[4], b[4];
        #pragma unroll
        for (int i = 0; i < 4; ++i)
            a[i] = *(const bf16x8*)(As + p * 4096 + (mg + i) * 512 + lane * 8);
        #pragma unroll
        for (int j = 0; j < 4; ++j)
            b[j] = *(const bf16x8*)(Bs + p * 4096 + (ng + j) * 512 + lane * 8);

        #pragma unroll
        for (int i = 0; i < 4; ++i)
            #pragma unroll
            for (int j = 0; j < 4; ++j)
                acc[i][j] = __builtin_amdgcn_mfma_f32_16x16x32_bf16(a[i], b[j], acc[i][j], 0, 0, 0);
    }
#undef STAGE

    // ---- fused LSTM gate epilogue -------------------------------------
    // Physical col of acc[i][k][r] = tileN*128 + (wave&1)*64 + 16k + (lane&15);
    // with the W-row permutation: gate = k, logical j = 16*q + (lane&15),
    // q = tileN*2 + (wave&1).
    const int j = ((tileN * 2 + (wave & 1)) << 4) | (lane & 15);
    const float bi = bh[j];
    const float bf = bh[j + 1024];
    const float bg = bh[j + 2048];
    const float bo = bh[j + 3072];

    const int row0 = tileM * 128 + (wave >> 1) * 64 + (lane >> 4) * 4;

    // batch all c loads first: one latency exposure, not 16 serialized ones
    float cv[4][4];
    #pragma unroll
    for (int i = 0; i < 4; ++i)
        #pragma unroll
        for (int r = 0; r < 4; ++r)
            cv[i][r] = c[(size_t)(row0 + i * 16 + r) * KH + j];

    #pragma unroll
    for (int i = 0; i < 4; ++i) {
        #pragma unroll
        for (int r = 0; r < 4; ++r) {
            const size_t idx = (size_t)(row0 + i * 16 + r) * KH + j;
            float iv = fsig(acc[i][0][r] + bi);
            float fv = fsig(acc[i][1][r] + bf);
            float gv = ftanh(acc[i][2][r] + bg);
            float ov = fsig(acc[i][3][r] + bo);
            float cn = fv * cv[i][r] + iv * gv;
            float hn = ov * ftanh(cn);
            out[idx] = hn;
            out[(size_t)ARR_ELEMS + idx] = cn;
        }
    }
}

// ----------------------------------------------------------------- launch ---
extern "C" void kernel_launch(void* const* d_in, const int* in_sizes, int n_in,
                              void* d_out, int out_size, void* d_ws, size_t ws_size,
                              hipStream_t stream) {
    const float* x  = (const float*)d_in[0];
    const float* h  = (const float*)d_in[1];
    const float* c  = (const float*)d_in[2];
    const float* Wh = (const float*)d_in[3];
    const float* bh = (const float*)d_in[4];
    const float* Wx = (const float*)d_in[5];
    float* out = (float*)d_out;

    unsigned short* ws   = (unsigned short*)d_ws;
    unsigned short* Acat = ws;                            // [4096 x 2048] bf16
    unsigned short* Wcat = ws + 2 * (size_t)ARR_ELEMS;    // [4096 x 2048] bf16 (rows permuted)

    convert_kernel<<<16384, 256, 0, stream>>>(h, x, Wh, Wx, Acat, Wcat);
    dim3 grid(32, 32);
    gemm_kernel<<<grid, 256, 0, stream>>>(Acat, Wcat, bh, c, out);
}

// Round 7
// 253.052 us; speedup vs baseline: 1.0248x; 1.0248x over previous
//
#include <hip/hip_runtime.h>
#include <cstdint>
#include <cstddef>

// LSTM cell: B=4096, IN=1024, H=1024
//   ifgo = h @ Wh^T + bh + x @ Wx^T    [4096 x 4096]
//   i,f,g,o = split(ifgo); c' = sig(f)*c + sig(i)*tanh(g); h' = o*tanh(c')
//
// Pipeline (2 dispatches):
//   1. convert: fp32->bf16 into interleaved K=2048 layout (A_cat=[h|x],
//      W_cat=[Wh|Wx]) with W rows permuted p=((j>>4)<<6)|(gate<<4)|(j&15)
//      so each wave's 64 output columns hold all 4 gates of 16 consecutive j.
//   2. gemm: bf16 MFMA, 128x128 tile, BK=64 two-barrier K-loop (R5 structure,
//      89.3us) + CHUNK-MAJOR LDS layout (R6-validated: bank conflicts 8.4M->0).
//      NOTE: do NOT issue ds_reads after pending global_load_lds into another
//      LDS buffer — compiler emits a conservative vmcnt(0) before the ds_reads
//      and serializes the pipeline (R6 regression, 151us).

#define NB   4096      // batch
#define KH   1024      // H (== IN)
#define KK   2048      // concatenated K
#define ARR_ELEMS 4194304  // 4096*1024

typedef __bf16 bf16x8 __attribute__((ext_vector_type(8)));
typedef float  f32x4  __attribute__((ext_vector_type(4)));

__device__ inline unsigned short f2bf(float f) {
    union { float f; unsigned int u; } v; v.f = f;
    unsigned int u = v.u;
    u += 0x7FFFu + ((u >> 16) & 1u);   // RNE
    return (unsigned short)(u >> 16);
}

// fast gates: v_exp_f32 + v_rcp_f32, no branches
__device__ inline float fsig(float v)  { return __builtin_amdgcn_rcpf(1.f + __expf(-v)); }
__device__ inline float ftanh(float v) { return 1.f - 2.f * __builtin_amdgcn_rcpf(1.f + __expf(2.f * v)); }

// ---------------------------------------------------------------- convert ---
// ws layout (bf16): A_cat (8M elems) | W_cat (8M elems)
__global__ void convert_kernel(const float* __restrict__ h, const float* __restrict__ x,
                               const float* __restrict__ Wh, const float* __restrict__ Wx,
                               unsigned short* __restrict__ A, unsigned short* __restrict__ W) {
    int idx = blockIdx.x * 256 + threadIdx.x;       // 0 .. 4M-1, 4 floats each
    int arr = idx >> 20;                            // which source array
    int off = (idx & 0xFFFFF) << 2;                 // element offset within array
    const float* src = (arr == 0) ? h : (arr == 1) ? x : (arr == 2) ? Wh : Wx;
    float4 v = *(const float4*)(src + off);
    unsigned int lo = (unsigned int)f2bf(v.x) | ((unsigned int)f2bf(v.y) << 16);
    unsigned int hi = (unsigned int)f2bf(v.z) | ((unsigned int)f2bf(v.w) << 16);
    uint2 packed; packed.x = lo; packed.y = hi;

    int row = off >> 10;                            // logical row
    int col = off & 1023;
    unsigned short* dst;
    size_t dstOff;
    if (arr < 2) {                                  // A_cat: [h | x] per row
        dst = A;
        dstOff = (size_t)row * KK + (arr == 1 ? 1024 : 0) + col;
    } else {                                        // W_cat: permuted rows, [Wh | Wx]
        int g = row >> 10, j = row & 1023;
        int p = ((j >> 4) << 6) | (g << 4) | (j & 15);
        dst = W;
        dstOff = (size_t)p * KK + (arr == 3 ? 1024 : 0) + col;
    }
    *(uint2*)(dst + dstOff) = packed;
}

// ------------------------------------------------------------------- gemm ---
// 256 threads (4 waves), each wave 64x64 via 4x4 MFMA 16x16x32 bf16.
// LDS chunk-major per 16-row group g, panel s: elem addr = s*4096 + g*512 +
// lane*8 with lane = (kchunk<<4) | rowlow  -> fragment reads are
// uniform + lane*16B (conflict-free), and exactly the MFMA A/B operand order.
// Staging: wave w, issue (s,q) loads group g=q*4+w of K-panel s: global row
// 16g+(lane&15), K-bytes panel_s*64 + (lane>>4)*16.
__global__ void gemm_kernel(const unsigned short* __restrict__ A,
                            const unsigned short* __restrict__ W,
                            const float* __restrict__ bh,
                            const float* __restrict__ c,
                            float* __restrict__ out) {
    __shared__ __align__(16) unsigned short As[2 * 4096];   // 2 K-panels x 128x32
    __shared__ __align__(16) unsigned short Bs[2 * 4096];

    const int tid  = threadIdx.x;
    const int wave = tid >> 6;
    const int lane = tid & 63;
    const int tileN = blockIdx.x;   // 0..31  (output cols / 128)
    const int tileM = blockIdx.y;   // 0..31  (output rows / 128)

    // global base: wave w's group rows start at 16w (+64 per q), lane covers
    // row (lane&15), K-chunk (lane>>4)
    const unsigned short* gaB = A + (size_t)(tileM * 128 + wave * 16 + (lane & 15)) * KK + (lane >> 4) * 8;
    const unsigned short* gbB = W + (size_t)(tileN * 128 + wave * 16 + (lane & 15)) * KK + (lane >> 4) * 8;

    const int mg = (wave >> 1) * 4;      // A row-group base for this wave's fragments
    const int ng = (wave & 1) * 4;       // B row-group base

    f32x4 acc[4][4] = {};

    for (int kt = 0; kt < 32; ++kt) {
        const unsigned short* ga = gaB + kt * 64;
        const unsigned short* gb = gbB + kt * 64;
        #pragma unroll
        for (int s = 0; s < 2; ++s) {          // K-panel
            #pragma unroll
            for (int q = 0; q < 2; ++q) {      // row-half (group g = q*4+wave)
                const size_t gOff = (size_t)(q * 64) * KK + s * 32;
                const int    lOff = s * 4096 + (q * 4 + wave) * 512;
                __builtin_amdgcn_global_load_lds(
                    (const __attribute__((address_space(1))) void*)(ga + gOff),
                    (__attribute__((address_space(3))) void*)(As + lOff), 16, 0, 0);
                __builtin_amdgcn_global_load_lds(
                    (const __attribute__((address_space(1))) void*)(gb + gOff),
                    (__attribute__((address_space(3))) void*)(Bs + lOff), 16, 0, 0);
            }
        }

        __syncthreads();

        #pragma unroll
        for (int s = 0; s < 2; ++s) {            // the two 32-K panels
            bf16x8 a[4], b[4];
            #pragma unroll
            for (int i = 0; i < 4; ++i)
                a[i] = *(const bf16x8*)(As + s * 4096 + (mg + i) * 512 + lane * 8);
            #pragma unroll
            for (int j = 0; j < 4; ++j)
                b[j] = *(const bf16x8*)(Bs + s * 4096 + (ng + j) * 512 + lane * 8);

            #pragma unroll
            for (int i = 0; i < 4; ++i)
                #pragma unroll
                for (int j = 0; j < 4; ++j)
                    acc[i][j] = __builtin_amdgcn_mfma_f32_16x16x32_bf16(a[i], b[j], acc[i][j], 0, 0, 0);
        }

        __syncthreads();
    }

    // ---- fused LSTM gate epilogue -------------------------------------
    // Physical col of acc[i][k][r] = tileN*128 + (wave&1)*64 + 16k + (lane&15);
    // with the W-row permutation: gate = k, logical j = 16*q + (lane&15),
    // q = tileN*2 + (wave&1).
    const int j = ((tileN * 2 + (wave & 1)) << 4) | (lane & 15);
    const float bi = bh[j];
    const float bf = bh[j + 1024];
    const float bg = bh[j + 2048];
    const float bo = bh[j + 3072];

    const int row0 = tileM * 128 + (wave >> 1) * 64 + (lane >> 4) * 4;

    // batch all c loads first: one latency exposure, not 16 serialized ones
    float cv[4][4];
    #pragma unroll
    for (int i = 0; i < 4; ++i)
        #pragma unroll
        for (int r = 0; r < 4; ++r)
            cv[i][r] = c[(size_t)(row0 + i * 16 + r) * KH + j];

    #pragma unroll
    for (int i = 0; i < 4; ++i) {
        #pragma unroll
        for (int r = 0; r < 4; ++r) {
            const size_t idx = (size_t)(row0 + i * 16 + r) * KH + j;
            float iv = fsig(acc[i][0][r] + bi);
            float fv = fsig(acc[i][1][r] + bf);
            float gv = ftanh(acc[i][2][r] + bg);
            float ov = fsig(acc[i][3][r] + bo);
            float cn = fv * cv[i][r] + iv * gv;
            float hn = ov * ftanh(cn);
            out[idx] = hn;
            out[(size_t)ARR_ELEMS + idx] = cn;
        }
    }
}

// ----------------------------------------------------------------- launch ---
extern "C" void kernel_launch(void* const* d_in, const int* in_sizes, int n_in,
                              void* d_out, int out_size, void* d_ws, size_t ws_size,
                              hipStream_t stream) {
    const float* x  = (const float*)d_in[0];
    const float* h  = (const float*)d_in[1];
    const float* c  = (const float*)d_in[2];
    const float* Wh = (const float*)d_in[3];
    const float* bh = (const float*)d_in[4];
    const float* Wx = (const float*)d_in[5];
    float* out = (float*)d_out;

    unsigned short* ws   = (unsigned short*)d_ws;
    unsigned short* Acat = ws;                            // [4096 x 2048] bf16
    unsigned short* Wcat = ws + 2 * (size_t)ARR_ELEMS;    // [4096 x 2048] bf16 (rows permuted)

    convert_kernel<<<16384, 256, 0, stream>>>(h, x, Wh, Wx, Acat, Wcat);
    dim3 grid(32, 32);
    gemm_kernel<<<grid, 256, 0, stream>>>(Acat, Wcat, bh, c, out);
}